// Round 2
// baseline (108.606 us; speedup 1.0000x reference)
//
#include <hip/hip_runtime.h>
#include <math.h>

#define NS 8192          // sampled points per part (24576/3)
#define NPTS 24576

// chamfer config
#define BXC 64           // threads per chamfer block (1 wave)
#define XPT 8            // x-points per thread
#define XB (NS / (BXC * XPT))   // 16 x-blocks
#define YSPLIT 64
#define YTILE (NS / YSPLIT)     // 128

#define RB 256           // reduce block size
#define RBLOCKS (4 * (NS / RB)) // 128 reduce blocks

typedef __attribute__((ext_vector_type(2))) float f32x2;

// ws float layout:
// [0..3]    accum per combo (combo = part*2 + dir)
// [36]      e_kin
// [37]      (uint) ticket counter for reduce finalize
// [64..]    float4 pts: transformed-cad[2][NS] then cam[2][NS]  (16*NS floats)
// [64+16*NS ..] partial mins: [4 combos][YSPLIT][NS]

__device__ inline void build_transform(const float* __restrict__ rot_quat,
                                       const float* __restrict__ tra,
                                       int p, float* t) {
    float a = rot_quat[p * 4 + 0], b = rot_quat[p * 4 + 1];
    float c = rot_quat[p * 4 + 2], d = rot_quat[p * 4 + 3];
    float inv = rsqrtf(a * a + b * b + c * c + d * d);
    a *= inv; b *= inv; c *= inv; d *= inv;
    t[0]  = 1.f - 2.f * c * c - 2.f * d * d;
    t[1]  = 2.f * b * c - 2.f * a * d;
    t[2]  = 2.f * a * c + 2.f * b * d;
    t[3]  = tra[p * 3 + 0];
    t[4]  = 2.f * b * c + 2.f * a * d;
    t[5]  = 1.f - 2.f * b * b - 2.f * d * d;
    t[6]  = 2.f * c * d - 2.f * a * b;
    t[7]  = tra[p * 3 + 1];
    t[8]  = 2.f * b * d - 2.f * a * c;
    t[9]  = 2.f * a * b + 2.f * c * d;
    t[10] = 1.f - 2.f * b * b - 2.f * c * c;
    t[11] = tra[p * 3 + 2];
    t[12] = 0.f; t[13] = 0.f; t[14] = 0.f; t[15] = 1.f;
}

// pack + prep fused: transforms points, writes pts; thread 0 also emits
// e_kin, transforms to out, and zeroes accumulators + ticket.
__global__ void pack_kernel(const float* __restrict__ cam_pts,
                            const float* __restrict__ cad_pts,
                            const float* __restrict__ rot_quat,
                            const float* __restrict__ tra,
                            const float* __restrict__ joint_axes,
                            float* __restrict__ ws,
                            float4* __restrict__ pts,
                            float* __restrict__ out) {
    int gid = blockIdx.x * blockDim.x + threadIdx.x;
    int p = gid >> 13;          // / NS
    int i = gid & (NS - 1);

    float T[16];
    build_transform(rot_quat, tra, p, T);

    int base = p * NPTS * 3 + i * 9;   // sample step 3, 3 floats each
    float x = cad_pts[base], y = cad_pts[base + 1], z = cad_pts[base + 2];
    float q0 = fmaf(T[0], x, fmaf(T[1], y, fmaf(T[2],  z, T[3])));
    float q1 = fmaf(T[4], x, fmaf(T[5], y, fmaf(T[6],  z, T[7])));
    float q2 = fmaf(T[8], x, fmaf(T[9], y, fmaf(T[10], z, T[11])));
    pts[p * NS + i] = make_float4(q0, q1, q2, fmaf(q0, q0, fmaf(q1, q1, q2 * q2)));
    float cx = cam_pts[base], cy = cam_pts[base + 1], cz = cam_pts[base + 2];
    pts[2 * NS + p * NS + i] =
        make_float4(cx, cy, cz, fmaf(cx, cx, fmaf(cy, cy, cz * cz)));

    if (gid == 0) {
        float T0[16], T1[16];
        build_transform(rot_quat, tra, 0, T0);
        build_transform(rot_quat, tra, 1, T1);
        for (int k = 0; k < 16; ++k) { out[2 + k] = T0[k]; out[18 + k] = T1[k]; }
        // e_kin: diff = T0 @ J0^T - T1 @ J1^T (4x2), Frobenius norm
        float ss = 0.f;
        for (int r = 0; r < 4; ++r)
            for (int j = 0; j < 2; ++j) {
                float d0 = 0.f, d1 = 0.f;
                for (int k = 0; k < 4; ++k) {
                    d0 += T0[r * 4 + k] * joint_axes[j * 4 + k];
                    d1 += T1[r * 4 + k] * joint_axes[8 + j * 4 + k];
                }
                float df = d0 - d1;
                ss += df * df;
            }
        float ek = 1.f / (1.f + expf(5.f * sqrtf(ss)));
        ws[36] = ek;
        out[1] = ek;
        ws[0] = 0.f; ws[1] = 0.f; ws[2] = 0.f; ws[3] = 0.f;
        ((unsigned*)ws)[37] = 0u;
    }
}

__global__ __launch_bounds__(BXC) void chamfer_kernel(const float4* __restrict__ pts,
                                                      float* __restrict__ partial) {
    int combo = blockIdx.y;           // p*2 + dir
    int p   = combo >> 1;
    int dir = combo & 1;
    const float4* X = pts + (dir == 0 ? p * NS : 2 * NS + p * NS);
    const float4* Y = pts + (dir == 0 ? 2 * NS + p * NS : p * NS);
    int ys = blockIdx.z;
    int xb = blockIdx.x;
    int t  = threadIdx.x;

    __shared__ float4 sy[YTILE];

    int xbase = xb * (BXC * XPT) + t;
    f32x2 m0[XPT / 2], m1[XPT / 2], m2[XPT / 2], s[XPT / 2], dmin[XPT / 2];
#pragma unroll
    for (int g = 0; g < XPT / 2; ++g) {
        float4 v0 = X[xbase + (2 * g) * BXC];
        float4 v1 = X[xbase + (2 * g + 1) * BXC];
        m0[g] = (f32x2){-2.f * v0.x, -2.f * v1.x};
        m1[g] = (f32x2){-2.f * v0.y, -2.f * v1.y};
        m2[g] = (f32x2){-2.f * v0.z, -2.f * v1.z};
        s[g]  = (f32x2){v0.w, v1.w};
        dmin[g] = (f32x2){3.4e38f, 3.4e38f};
    }

    int ybase = ys * YTILE;
#pragma unroll
    for (int c = 0; c < YTILE / BXC; ++c)
        sy[t + c * BXC] = Y[ybase + c * BXC + t];
    __syncthreads();

#pragma unroll 4
    for (int j = 0; j < YTILE; ++j) {
        float4 y = sy[j];
        f32x2 yw = (f32x2){y.w, y.w};
        f32x2 yx = (f32x2){y.x, y.x};
        f32x2 yy = (f32x2){y.y, y.y};
        f32x2 yz = (f32x2){y.z, y.z};
#pragma unroll
        for (int g = 0; g < XPT / 2; ++g) {
            f32x2 d = s[g] + yw;
            d = __builtin_elementwise_fma(m0[g], yx, d);
            d = __builtin_elementwise_fma(m1[g], yy, d);
            d = __builtin_elementwise_fma(m2[g], yz, d);
            dmin[g] = __builtin_elementwise_min(dmin[g], d);
        }
    }

    float* prow = partial + (combo * YSPLIT + ys) * NS + xbase;
#pragma unroll
    for (int g = 0; g < XPT / 2; ++g) {
        prow[(2 * g) * BXC]     = dmin[g].x;
        prow[(2 * g + 1) * BXC] = dmin[g].y;
    }
}

// reduce + finalize fused (last-block ticket)
__global__ void reduce_kernel(const float* __restrict__ partial,
                              const float* __restrict__ pw,
                              float* __restrict__ ws,
                              float* __restrict__ out) {
    int combo = blockIdx.y;
    int x = blockIdx.x * RB + threadIdx.x;
    const float* p = partial + combo * (YSPLIT * NS) + x;
    float m = 3.4e38f;
#pragma unroll 8
    for (int ysi = 0; ysi < YSPLIT; ++ysi) m = fminf(m, p[ysi * NS]);
    float d = sqrtf(fmaxf(m, 0.f));
#pragma unroll
    for (int off = 32; off > 0; off >>= 1) d += __shfl_down(d, off, 64);
    __shared__ float sm[RB / 64];
    int wid = threadIdx.x >> 6;
    if ((threadIdx.x & 63) == 0) sm[wid] = d;
    __syncthreads();
    if (threadIdx.x == 0) {
        float sum = 0.f;
        for (int w = 0; w < RB / 64; ++w) sum += sm[w];
        atomicAdd(&ws[combo], sum);
        __threadfence();
        unsigned old = atomicAdd(&((unsigned*)ws)[37], 1u);
        if (old == RBLOCKS - 1) {
            // all blocks' accumulations are visible (fence-before-ticket)
            float a0 = atomicAdd(&ws[0], 0.f);
            float a1 = atomicAdd(&ws[1], 0.f);
            float a2 = atomicAdd(&ws[2], 0.f);
            float a3 = atomicAdd(&ws[3], 0.f);
            float e0 = (a0 + a1) * (1.f / NS);
            float e1 = (a2 + a3) * (1.f / NS);
            out[0] = pw[0] * e0 + pw[1] * e1 + pw[2] * ws[36];
        }
    }
}

extern "C" void kernel_launch(void* const* d_in, const int* in_sizes, int n_in,
                              void* d_out, int out_size, void* d_ws, size_t ws_size,
                              hipStream_t stream) {
    const float* cam = (const float*)d_in[0];
    const float* cad = (const float*)d_in[1];
    const float* pw  = (const float*)d_in[2];
    const float* rq  = (const float*)d_in[3];
    const float* tr  = (const float*)d_in[4];
    const float* ja  = (const float*)d_in[5];
    float* out = (float*)d_out;
    float* ws  = (float*)d_ws;
    float4* pts = (float4*)(ws + 64);
    float* partial = ws + 64 + 16 * NS;   // after 4*NS float4s

    pack_kernel<<<(2 * NS) / 256, 256, 0, stream>>>(cam, cad, rq, tr, ja, ws, pts, out);
    dim3 cg(XB, 4, YSPLIT);
    chamfer_kernel<<<cg, BXC, 0, stream>>>(pts, partial);
    reduce_kernel<<<dim3(NS / RB, 4), RB, 0, stream>>>(partial, pw, ws, out);
}

// Round 3
// 105.184 us; speedup vs baseline: 1.0325x; 1.0325x over previous
//
#include <hip/hip_runtime.h>
#include <math.h>

#define NS 8192          // sampled points per part (24576/3)
#define NPTS 24576

// chamfer config
#define BXC 64           // threads per chamfer block (1 wave)
#define XPT 16           // x-points per thread
#define XB (NS / (BXC * XPT))   // 8 x-blocks
#define YSPLIT 64
#define YTILE (NS / YSPLIT)     // 128

#define RB 256           // reduce block size
#define RBLOCKS (4 * (NS / RB)) // 128 reduce blocks

typedef __attribute__((ext_vector_type(2))) float f32x2;

// ws float layout:
// [0..3]    accum per combo (combo = part*2 + dir)
// [36]      e_kin
// [37]      (uint) ticket counter for reduce finalize
// [64..]    float4 pts: transformed-cad[2][NS] then cam[2][NS]  (16*NS floats)
// [64+16*NS ..] partial mins: [4 combos][YSPLIT][NS]  (includes +|x|^2)

__device__ inline void build_transform(const float* __restrict__ rot_quat,
                                       const float* __restrict__ tra,
                                       int p, float* t) {
    float a = rot_quat[p * 4 + 0], b = rot_quat[p * 4 + 1];
    float c = rot_quat[p * 4 + 2], d = rot_quat[p * 4 + 3];
    float inv = rsqrtf(a * a + b * b + c * c + d * d);
    a *= inv; b *= inv; c *= inv; d *= inv;
    t[0]  = 1.f - 2.f * c * c - 2.f * d * d;
    t[1]  = 2.f * b * c - 2.f * a * d;
    t[2]  = 2.f * a * c + 2.f * b * d;
    t[3]  = tra[p * 3 + 0];
    t[4]  = 2.f * b * c + 2.f * a * d;
    t[5]  = 1.f - 2.f * b * b - 2.f * d * d;
    t[6]  = 2.f * c * d - 2.f * a * b;
    t[7]  = tra[p * 3 + 1];
    t[8]  = 2.f * b * d - 2.f * a * c;
    t[9]  = 2.f * a * b + 2.f * c * d;
    t[10] = 1.f - 2.f * b * b - 2.f * c * c;
    t[11] = tra[p * 3 + 2];
    t[12] = 0.f; t[13] = 0.f; t[14] = 0.f; t[15] = 1.f;
}

// pack + prep fused
__global__ void pack_kernel(const float* __restrict__ cam_pts,
                            const float* __restrict__ cad_pts,
                            const float* __restrict__ rot_quat,
                            const float* __restrict__ tra,
                            const float* __restrict__ joint_axes,
                            float* __restrict__ ws,
                            float4* __restrict__ pts,
                            float* __restrict__ out) {
    int gid = blockIdx.x * blockDim.x + threadIdx.x;
    int p = gid >> 13;          // / NS
    int i = gid & (NS - 1);

    float T[16];
    build_transform(rot_quat, tra, p, T);

    int base = p * NPTS * 3 + i * 9;   // sample step 3, 3 floats each
    float x = cad_pts[base], y = cad_pts[base + 1], z = cad_pts[base + 2];
    float q0 = fmaf(T[0], x, fmaf(T[1], y, fmaf(T[2],  z, T[3])));
    float q1 = fmaf(T[4], x, fmaf(T[5], y, fmaf(T[6],  z, T[7])));
    float q2 = fmaf(T[8], x, fmaf(T[9], y, fmaf(T[10], z, T[11])));
    pts[p * NS + i] = make_float4(q0, q1, q2, fmaf(q0, q0, fmaf(q1, q1, q2 * q2)));
    float cx = cam_pts[base], cy = cam_pts[base + 1], cz = cam_pts[base + 2];
    pts[2 * NS + p * NS + i] =
        make_float4(cx, cy, cz, fmaf(cx, cx, fmaf(cy, cy, cz * cz)));

    if (gid == 0) {
        float T0[16], T1[16];
        build_transform(rot_quat, tra, 0, T0);
        build_transform(rot_quat, tra, 1, T1);
        for (int k = 0; k < 16; ++k) { out[2 + k] = T0[k]; out[18 + k] = T1[k]; }
        float ss = 0.f;
        for (int r = 0; r < 4; ++r)
            for (int j = 0; j < 2; ++j) {
                float d0 = 0.f, d1 = 0.f;
                for (int k = 0; k < 4; ++k) {
                    d0 += T0[r * 4 + k] * joint_axes[j * 4 + k];
                    d1 += T1[r * 4 + k] * joint_axes[8 + j * 4 + k];
                }
                float df = d0 - d1;
                ss += df * df;
            }
        float ek = 1.f / (1.f + expf(5.f * sqrtf(ss)));
        ws[36] = ek;
        out[1] = ek;
        ws[0] = 0.f; ws[1] = 0.f; ws[2] = 0.f; ws[3] = 0.f;
        ((unsigned*)ws)[37] = 0u;
    }
}

__global__ __launch_bounds__(BXC) void chamfer_kernel(const float4* __restrict__ pts,
                                                      float* __restrict__ partial) {
    int combo = blockIdx.y;           // p*2 + dir
    int p   = combo >> 1;
    int dir = combo & 1;
    const float4* X = pts + (dir == 0 ? p * NS : 2 * NS + p * NS);
    const float4* Y = pts + (dir == 0 ? 2 * NS + p * NS : p * NS);
    int ys = blockIdx.z;
    int xb = blockIdx.x;
    int t  = threadIdx.x;

    __shared__ float4 sy[YTILE];

    int xbase = xb * (BXC * XPT) + t;
    f32x2 m0[XPT / 2], m1[XPT / 2], m2[XPT / 2], s[XPT / 2], dmin[XPT / 2];
#pragma unroll
    for (int g = 0; g < XPT / 2; ++g) {
        float4 v0 = X[xbase + (2 * g) * BXC];
        float4 v1 = X[xbase + (2 * g + 1) * BXC];
        m0[g] = (f32x2){-2.f * v0.x, -2.f * v1.x};
        m1[g] = (f32x2){-2.f * v0.y, -2.f * v1.y};
        m2[g] = (f32x2){-2.f * v0.z, -2.f * v1.z};
        s[g]  = (f32x2){v0.w, v1.w};
        dmin[g] = (f32x2){3.4e38f, 3.4e38f};
    }

    int ybase = ys * YTILE;
#pragma unroll
    for (int c = 0; c < YTILE / BXC; ++c)
        sy[t + c * BXC] = Y[ybase + c * BXC + t];
    __syncthreads();

    // min_j (|y|^2 - 2 x.y); |x|^2 added in epilogue
#pragma unroll 4
    for (int j = 0; j < YTILE; ++j) {
        float4 y = sy[j];
        f32x2 yw = (f32x2){y.w, y.w};
        f32x2 yx = (f32x2){y.x, y.x};
        f32x2 yy = (f32x2){y.y, y.y};
        f32x2 yz = (f32x2){y.z, y.z};
#pragma unroll
        for (int g = 0; g < XPT / 2; ++g) {
            f32x2 d = __builtin_elementwise_fma(m0[g], yx, yw);
            d = __builtin_elementwise_fma(m1[g], yy, d);
            d = __builtin_elementwise_fma(m2[g], yz, d);
            dmin[g] = __builtin_elementwise_min(dmin[g], d);
        }
    }

    float* prow = partial + (combo * YSPLIT + ys) * NS + xbase;
#pragma unroll
    for (int g = 0; g < XPT / 2; ++g) {
        f32x2 v = dmin[g] + s[g];
        prow[(2 * g) * BXC]     = v.x;
        prow[(2 * g + 1) * BXC] = v.y;
    }
}

// reduce + finalize fused (last-block ticket)
__global__ void reduce_kernel(const float* __restrict__ partial,
                              const float* __restrict__ pw,
                              float* __restrict__ ws,
                              float* __restrict__ out) {
    int combo = blockIdx.y;
    int x = blockIdx.x * RB + threadIdx.x;
    const float* p = partial + combo * (YSPLIT * NS) + x;
    float m = 3.4e38f;
#pragma unroll 8
    for (int ysi = 0; ysi < YSPLIT; ++ysi) m = fminf(m, p[ysi * NS]);
    float d = sqrtf(fmaxf(m, 0.f));
#pragma unroll
    for (int off = 32; off > 0; off >>= 1) d += __shfl_down(d, off, 64);
    __shared__ float sm[RB / 64];
    int wid = threadIdx.x >> 6;
    if ((threadIdx.x & 63) == 0) sm[wid] = d;
    __syncthreads();
    if (threadIdx.x == 0) {
        float sum = 0.f;
        for (int w = 0; w < RB / 64; ++w) sum += sm[w];
        atomicAdd(&ws[combo], sum);
        __threadfence();
        unsigned old = atomicAdd(&((unsigned*)ws)[37], 1u);
        if (old == RBLOCKS - 1) {
            float a0 = atomicAdd(&ws[0], 0.f);
            float a1 = atomicAdd(&ws[1], 0.f);
            float a2 = atomicAdd(&ws[2], 0.f);
            float a3 = atomicAdd(&ws[3], 0.f);
            float e0 = (a0 + a1) * (1.f / NS);
            float e1 = (a2 + a3) * (1.f / NS);
            out[0] = pw[0] * e0 + pw[1] * e1 + pw[2] * ws[36];
        }
    }
}

extern "C" void kernel_launch(void* const* d_in, const int* in_sizes, int n_in,
                              void* d_out, int out_size, void* d_ws, size_t ws_size,
                              hipStream_t stream) {
    const float* cam = (const float*)d_in[0];
    const float* cad = (const float*)d_in[1];
    const float* pw  = (const float*)d_in[2];
    const float* rq  = (const float*)d_in[3];
    const float* tr  = (const float*)d_in[4];
    const float* ja  = (const float*)d_in[5];
    float* out = (float*)d_out;
    float* ws  = (float*)d_ws;
    float4* pts = (float4*)(ws + 64);
    float* partial = ws + 64 + 16 * NS;   // after 4*NS float4s

    pack_kernel<<<(2 * NS) / 256, 256, 0, stream>>>(cam, cad, rq, tr, ja, ws, pts, out);
    dim3 cg(XB, 4, YSPLIT);
    chamfer_kernel<<<cg, BXC, 0, stream>>>(pts, partial);
    reduce_kernel<<<dim3(NS / RB, 4), RB, 0, stream>>>(partial, pw, ws, out);
}